// Round 13
// baseline (144.511 us; speedup 1.0000x reference)
//
#include <hip/hip_runtime.h>

// adder2d: out[b,f,l] = -sum_k |W[f,k] - P[b,k,l]|, P = 3x3/s1/p1 im2col of x.
// Round-13: r11 (4-wave blocks, 64m x 128f, shared staging, v_sad_u16,
// reg-prefetch, K-split slabs + combine) with SINGLE-buffer LDS (13.8 KB,
// was 27.6 double-buffered) so ~6 blocks/CU are co-resident (launch_bounds
// (256,6)); extra raw s_barrier per chunk for read-drain before overwrite
// (reads are data-dependency-drained; prefetch vmcnt stays in flight).

#define B_    16
#define C_    128
#define HH    28
#define WW    28
#define F_    128
#define L_    (HH * WW)          // 784
#define K_    (C_ * 9)           // 1152
#define M_    (B_ * L_)          // 12544 = 196 * 64 exactly
#define TM    64
#define BC    4                  // channels per chunk
#define KC    (BC * 9)           // 36 k per chunk
#define KP    (KC / 2)           // 18 packed pairs per chunk
#define SLAB  (B_ * F_ * L_)     // 1,605,632 floats per partial slab
#define NMT   (M_ / TM)          // 196 m-tiles
#define QS    4096.0f            // u16 quantization scale (range +-8)
#define QB    32768.5f           // bias + 0.5 (round-half-up via cvt floor)

__device__ __forceinline__ unsigned sad16(unsigned a, unsigned b, unsigned c) {
    // D = |a.lo16 - b.lo16| + |a.hi16 - b.hi16| + c   (2 elems / inst)
    asm("v_sad_u16 %0, %1, %2, %0" : "+v"(c) : "v"(a), "v"(b));
    return c;
}

__global__ __launch_bounds__(256, 6)
void adder2d_main(const float* __restrict__ x, const float* __restrict__ Wg,
                  float* __restrict__ dst, int nch, int direct) {
    __shared__ __align__(16) unsigned Plq[KP][TM];   //  4,608 B
    __shared__ __align__(16) unsigned Wlq[KP][F_];   //  9,216 B

    const int t    = threadIdx.x;       // 0..255
    const int lane = t & 63;
    const int w    = t >> 6;            // wave 0..3
    const int tx   = lane & 7;          // m-group: 8 m each
    const int ty   = lane >> 3;         // f-group: 4 f each
    const int fw   = 32 * w;            // wave's f slice base
    const int mt   = blockIdx.x, sp = blockIdx.z;
    const int c0   = sp * nch * BC;

    // ---- P identity: lane owns m = mt*64 + lane (same set in every wave) ----
    const int m  = mt * TM + lane;
    const int b  = m / L_;
    const int l  = m - b * L_;
    const int ho = l / WW, wo = l - ho * WW;
    int   toff[9];
    float sc[9];
    #pragma unroll
    for (int r = 0; r < 9; ++r) {
        const int dy = r / 3 - 1;
        const int dx = r - (r / 3) * 3 - 1;
        const bool ok = ((unsigned)(ho + dy) < (unsigned)HH) &&
                        ((unsigned)(wo + dx) < (unsigned)WW);
        toff[r] = ok ? (dy * WW + dx) : 0;   // safe addr; zeroed by sc
        sc[r]   = ok ? QS : 0.0f;            // masked -> quantize(0) = bias
    }
    const float* xb = x + (size_t)b * (C_ * L_) + l;

    // ---- staging roles (wave-uniform) ----
    // P: wave w stages channel-pair cp = w>>1 (channels c8+cp, c8+cp+2),
    //    taps r in [r0, r0+5): waves 0/2 -> taps 0-4, waves 1/3 -> 5-8.
    const int cp = w >> 1;
    const int r0 = (w & 1) ? 5 : 0;
    // W: thread owns row fW = t>>1, pair-half pW = t&1 -> words kp = pW*9 + i.
    const int fW = t >> 1;
    const int pW = t & 1;
    const float* wbase = Wg + (size_t)fW * K_;

    unsigned acc[8][4];
    #pragma unroll
    for (int i = 0; i < 8; ++i)
        #pragma unroll
        for (int j = 0; j < 4; ++j) acc[i][j] = 0u;

    // ---- prefetch registers ----
    float ppre[10];     // P: 5 taps x 2 channels (5th unused for odd waves)
    float wpre[18];     // W: 9 taps x 2 channels

    auto loadP = [&](int c8) {
        const float* x1 = xb + (size_t)(c8 + cp) * L_;
        const float* x2 = x1 + 2 * L_;
        #pragma unroll
        for (int i = 0; i < 5; ++i) {
            const int r  = r0 + i;
            const int rr = (r > 8) ? 8 : r;      // clamp (dup load, not stored)
            ppre[i]     = x1[toff[rr]];
            ppre[5 + i] = x2[toff[rr]];
        }
    };
    auto loadW = [&](int c8) {
        const float* w1 = wbase + (size_t)(c8 + pW) * 9;
        #pragma unroll
        for (int i = 0; i < 9; ++i) {            // consecutive -> merged loads
            wpre[i]     = w1[i];
            wpre[9 + i] = w1[18 + i];            // channel c8+pW+2
        }
    };

    loadP(c0);
    loadW(c0);

    #pragma unroll 1
    for (int ch = 0; ch < nch; ++ch) {
        // ---- write staged regs -> LDS (quantize + pack inline) ----
        #pragma unroll
        for (int i = 0; i < 5; ++i) {
            const int r = r0 + i;
            if (r <= 8) {
                const unsigned qlo = (unsigned)__builtin_fmaf(ppre[i],     sc[r], QB);
                const unsigned qhi = (unsigned)__builtin_fmaf(ppre[5 + i], sc[r], QB);
                Plq[cp * 9 + r][lane] = (qlo & 0xffffu) | (qhi << 16);
            }
        }
        #pragma unroll
        for (int i = 0; i < 9; ++i) {
            const unsigned qlo = (unsigned)__builtin_fmaf(wpre[i],     QS, QB);
            const unsigned qhi = (unsigned)__builtin_fmaf(wpre[9 + i], QS, QB);
            Wlq[pW * 9 + i][fW] = (qlo & 0xffffu) | (qhi << 16);
        }
        // ---- prefetch next chunk (stays in flight across the barrier) ----
        if (ch + 1 < nch) {
            loadP(c0 + (ch + 1) * BC);
            loadW(c0 + (ch + 1) * BC);
        }
        // ---- barrier A: LDS writes drained, vmcnt NOT drained ----
        asm volatile("s_waitcnt lgkmcnt(0)" ::: "memory");
        __builtin_amdgcn_s_barrier();
        asm volatile("" ::: "memory");
        __builtin_amdgcn_sched_barrier(0);
        // ---- compute: 18 kp x (3 ds_read_b128 + 32 v_sad_u16) ----
        #pragma unroll 6
        for (int kp = 0; kp < KP; ++kp) {
            const uint4 pA = *(const uint4*)&Plq[kp][tx * 8];
            const uint4 pB = *(const uint4*)&Plq[kp][tx * 8 + 4];
            const uint4 wA = *(const uint4*)&Wlq[kp][fw + ty * 4];
            const unsigned pm[8] = {pA.x, pA.y, pA.z, pA.w,
                                    pB.x, pB.y, pB.z, pB.w};
            const unsigned wn[4] = {wA.x, wA.y, wA.z, wA.w};
            #pragma unroll
            for (int i = 0; i < 8; ++i)
                #pragma unroll
                for (int j = 0; j < 4; ++j)
                    acc[i][j] = sad16(pm[i], wn[j], acc[i][j]);
        }
        // ---- barrier B: every wave's reads of this buffer are consumed
        // (data deps drained lgkmcnt) before anyone's next-chunk writes ----
        if (ch + 1 < nch) {
            asm volatile("" ::: "memory");
            __builtin_amdgcn_sched_barrier(0);
            __builtin_amdgcn_s_barrier();
            asm volatile("" ::: "memory");
        }
    }

    // ---- store: thread covers m = mt*64 + tx*8 .. +8 (8 | 784: no straddle)
    const int mb = mt * TM + tx * 8;
    const int bI = mb / L_;
    const int lb = mb - bI * L_;
    float* slab = direct ? dst : dst + (size_t)sp * SLAB;
    const float qs = (direct ? -1.0f : 1.0f) / QS;   // dequant + sign fold
    #pragma unroll
    for (int j = 0; j < 4; ++j) {
        const int f = fw + ty * 4 + j;
        float* o = &slab[(size_t)(bI * F_ + f) * L_ + lb];
        *(float4*)o       = make_float4(qs * (float)acc[0][j], qs * (float)acc[1][j],
                                        qs * (float)acc[2][j], qs * (float)acc[3][j]);
        *(float4*)(o + 4) = make_float4(qs * (float)acc[4][j], qs * (float)acc[5][j],
                                        qs * (float)acc[6][j], qs * (float)acc[7][j]);
    }
}

__global__ __launch_bounds__(256)
void adder2d_combine(const float* __restrict__ ws, float* __restrict__ out,
                     int nslab) {
    const int i = blockIdx.x * 256 + threadIdx.x;     // float4 index, SLAB/4 total
    float4 r = make_float4(0.0f, 0.0f, 0.0f, 0.0f);
    for (int s = 0; s < nslab; ++s) {
        const float4 p = ((const float4*)(ws + (size_t)s * SLAB))[i];
        r.x += p.x; r.y += p.y; r.z += p.z; r.w += p.w;
    }
    ((float4*)out)[i] = make_float4(-r.x, -r.y, -r.z, -r.w);
}

extern "C" void kernel_launch(void* const* d_in, const int* in_sizes, int n_in,
                              void* d_out, int out_size, void* d_ws, size_t ws_size,
                              hipStream_t stream) {
    const float* x = (const float*)d_in[0];   // [16,128,28,28]
    const float* W = (const float*)d_in[1];   // [128,128,3,3]
    float* out = (float*)d_out;               // [16,128,28,28]
    float* ws  = (float*)d_ws;

    int split = 0;
    if (ws_size >= (size_t)8 * SLAB * sizeof(float))      split = 8;  // 51.4 MB
    else if (ws_size >= (size_t)4 * SLAB * sizeof(float)) split = 4;  // 25.7 MB

    if (split) {
        dim3 grid(NMT, 1, split);             // 196 x split 4-wave blocks
        adder2d_main<<<grid, 256, 0, stream>>>(x, W, ws, (C_ / BC) / split, 0);
        adder2d_combine<<<SLAB / 4 / 256, 256, 0, stream>>>(ws, out, split);
    } else {
        dim3 grid(NMT, 1, 1);                 // fallback: direct, full K
        adder2d_main<<<grid, 256, 0, stream>>>(x, W, out, C_ / BC, 1);
    }
}

// Round 14
// 112.789 us; speedup vs baseline: 1.2813x; 1.2813x over previous
//
#include <hip/hip_runtime.h>

// adder2d: out[b,f,l] = -sum_k |W[f,k] - P[b,k,l]|, P = 3x3/s1/p1 im2col of x.
// Round-14: r13 structure (4-wave blocks, 64m x 128f, shared staging,
// v_sad_u16, SINGLE-buffer LDS 13.8KB, two raw barriers/chunk, K-split
// slabs + combine) with launch_bounds (256,6)->(256,4): VGPR cap 128 covers
// the ~95-reg live set -> NO SPILL (r13's 122MB scratch WRITE_SIZE was the
// whole regression), while LDS at 13.8KB still admits ~5 blocks/CU.

#define B_    16
#define C_    128
#define HH    28
#define WW    28
#define F_    128
#define L_    (HH * WW)          // 784
#define K_    (C_ * 9)           // 1152
#define M_    (B_ * L_)          // 12544 = 196 * 64 exactly
#define TM    64
#define BC    4                  // channels per chunk
#define KC    (BC * 9)           // 36 k per chunk
#define KP    (KC / 2)           // 18 packed pairs per chunk
#define SLAB  (B_ * F_ * L_)     // 1,605,632 floats per partial slab
#define NMT   (M_ / TM)          // 196 m-tiles
#define QS    4096.0f            // u16 quantization scale (range +-8)
#define QB    32768.5f           // bias + 0.5 (round-half-up via cvt floor)

__device__ __forceinline__ unsigned sad16(unsigned a, unsigned b, unsigned c) {
    // D = |a.lo16 - b.lo16| + |a.hi16 - b.hi16| + c   (2 elems / inst)
    asm("v_sad_u16 %0, %1, %2, %0" : "+v"(c) : "v"(a), "v"(b));
    return c;
}

__global__ __launch_bounds__(256, 4)
void adder2d_main(const float* __restrict__ x, const float* __restrict__ Wg,
                  float* __restrict__ dst, int nch, int direct) {
    __shared__ __align__(16) unsigned Plq[KP][TM];   //  4,608 B
    __shared__ __align__(16) unsigned Wlq[KP][F_];   //  9,216 B

    const int t    = threadIdx.x;       // 0..255
    const int lane = t & 63;
    const int w    = t >> 6;            // wave 0..3
    const int tx   = lane & 7;          // m-group: 8 m each
    const int ty   = lane >> 3;         // f-group: 4 f each
    const int fw   = 32 * w;            // wave's f slice base
    const int mt   = blockIdx.x, sp = blockIdx.z;
    const int c0   = sp * nch * BC;

    // ---- P identity: lane owns m = mt*64 + lane (same set in every wave) ----
    const int m  = mt * TM + lane;
    const int b  = m / L_;
    const int l  = m - b * L_;
    const int ho = l / WW, wo = l - ho * WW;
    int   toff[9];
    float sc[9];
    #pragma unroll
    for (int r = 0; r < 9; ++r) {
        const int dy = r / 3 - 1;
        const int dx = r - (r / 3) * 3 - 1;
        const bool ok = ((unsigned)(ho + dy) < (unsigned)HH) &&
                        ((unsigned)(wo + dx) < (unsigned)WW);
        toff[r] = ok ? (dy * WW + dx) : 0;   // safe addr; zeroed by sc
        sc[r]   = ok ? QS : 0.0f;            // masked -> quantize(0) = bias
    }
    const float* xb = x + (size_t)b * (C_ * L_) + l;

    // ---- staging roles (wave-uniform) ----
    // P: wave w stages channel-pair cp = w>>1 (channels c8+cp, c8+cp+2),
    //    taps r in [r0, r0+5): waves 0/2 -> taps 0-4, waves 1/3 -> 5-8.
    const int cp = w >> 1;
    const int r0 = (w & 1) ? 5 : 0;
    // W: thread owns row fW = t>>1, pair-half pW = t&1 -> words kp = pW*9 + i.
    const int fW = t >> 1;
    const int pW = t & 1;
    const float* wbase = Wg + (size_t)fW * K_;

    unsigned acc[8][4];
    #pragma unroll
    for (int i = 0; i < 8; ++i)
        #pragma unroll
        for (int j = 0; j < 4; ++j) acc[i][j] = 0u;

    // ---- prefetch registers ----
    float ppre[10];     // P: 5 taps x 2 channels (5th unused for odd waves)
    float wpre[18];     // W: 9 taps x 2 channels

    auto loadP = [&](int c8) {
        const float* x1 = xb + (size_t)(c8 + cp) * L_;
        const float* x2 = x1 + 2 * L_;
        #pragma unroll
        for (int i = 0; i < 5; ++i) {
            const int r  = r0 + i;
            const int rr = (r > 8) ? 8 : r;      // clamp (dup load, not stored)
            ppre[i]     = x1[toff[rr]];
            ppre[5 + i] = x2[toff[rr]];
        }
    };
    auto loadW = [&](int c8) {
        const float* w1 = wbase + (size_t)(c8 + pW) * 9;
        #pragma unroll
        for (int i = 0; i < 9; ++i) {            // consecutive -> merged loads
            wpre[i]     = w1[i];
            wpre[9 + i] = w1[18 + i];            // channel c8+pW+2
        }
    };

    loadP(c0);
    loadW(c0);

    #pragma unroll 1
    for (int ch = 0; ch < nch; ++ch) {
        // ---- write staged regs -> LDS (quantize + pack inline) ----
        #pragma unroll
        for (int i = 0; i < 5; ++i) {
            const int r = r0 + i;
            if (r <= 8) {
                const unsigned qlo = (unsigned)__builtin_fmaf(ppre[i],     sc[r], QB);
                const unsigned qhi = (unsigned)__builtin_fmaf(ppre[5 + i], sc[r], QB);
                Plq[cp * 9 + r][lane] = (qlo & 0xffffu) | (qhi << 16);
            }
        }
        #pragma unroll
        for (int i = 0; i < 9; ++i) {
            const unsigned qlo = (unsigned)__builtin_fmaf(wpre[i],     QS, QB);
            const unsigned qhi = (unsigned)__builtin_fmaf(wpre[9 + i], QS, QB);
            Wlq[pW * 9 + i][fW] = (qlo & 0xffffu) | (qhi << 16);
        }
        // ---- prefetch next chunk (stays in flight across the barrier) ----
        if (ch + 1 < nch) {
            loadP(c0 + (ch + 1) * BC);
            loadW(c0 + (ch + 1) * BC);
        }
        // ---- barrier A: LDS writes drained, vmcnt NOT drained ----
        asm volatile("s_waitcnt lgkmcnt(0)" ::: "memory");
        __builtin_amdgcn_s_barrier();
        asm volatile("" ::: "memory");
        __builtin_amdgcn_sched_barrier(0);
        // ---- compute: 18 kp x (3 ds_read_b128 + 32 v_sad_u16) ----
        #pragma unroll 6
        for (int kp = 0; kp < KP; ++kp) {
            const uint4 pA = *(const uint4*)&Plq[kp][tx * 8];
            const uint4 pB = *(const uint4*)&Plq[kp][tx * 8 + 4];
            const uint4 wA = *(const uint4*)&Wlq[kp][fw + ty * 4];
            const unsigned pm[8] = {pA.x, pA.y, pA.z, pA.w,
                                    pB.x, pB.y, pB.z, pB.w};
            const unsigned wn[4] = {wA.x, wA.y, wA.z, wA.w};
            #pragma unroll
            for (int i = 0; i < 8; ++i)
                #pragma unroll
                for (int j = 0; j < 4; ++j)
                    acc[i][j] = sad16(pm[i], wn[j], acc[i][j]);
        }
        // ---- barrier B: every wave's reads of this buffer are consumed
        // (data deps drained lgkmcnt) before anyone's next-chunk writes ----
        if (ch + 1 < nch) {
            asm volatile("" ::: "memory");
            __builtin_amdgcn_sched_barrier(0);
            __builtin_amdgcn_s_barrier();
            asm volatile("" ::: "memory");
        }
    }

    // ---- store: thread covers m = mt*64 + tx*8 .. +8 (8 | 784: no straddle)
    const int mb = mt * TM + tx * 8;
    const int bI = mb / L_;
    const int lb = mb - bI * L_;
    float* slab = direct ? dst : dst + (size_t)sp * SLAB;
    const float qs = (direct ? -1.0f : 1.0f) / QS;   // dequant + sign fold
    #pragma unroll
    for (int j = 0; j < 4; ++j) {
        const int f = fw + ty * 4 + j;
        float* o = &slab[(size_t)(bI * F_ + f) * L_ + lb];
        *(float4*)o       = make_float4(qs * (float)acc[0][j], qs * (float)acc[1][j],
                                        qs * (float)acc[2][j], qs * (float)acc[3][j]);
        *(float4*)(o + 4) = make_float4(qs * (float)acc[4][j], qs * (float)acc[5][j],
                                        qs * (float)acc[6][j], qs * (float)acc[7][j]);
    }
}

__global__ __launch_bounds__(256)
void adder2d_combine(const float* __restrict__ ws, float* __restrict__ out,
                     int nslab) {
    const int i = blockIdx.x * 256 + threadIdx.x;     // float4 index, SLAB/4 total
    float4 r = make_float4(0.0f, 0.0f, 0.0f, 0.0f);
    for (int s = 0; s < nslab; ++s) {
        const float4 p = ((const float4*)(ws + (size_t)s * SLAB))[i];
        r.x += p.x; r.y += p.y; r.z += p.z; r.w += p.w;
    }
    ((float4*)out)[i] = make_float4(-r.x, -r.y, -r.z, -r.w);
}

extern "C" void kernel_launch(void* const* d_in, const int* in_sizes, int n_in,
                              void* d_out, int out_size, void* d_ws, size_t ws_size,
                              hipStream_t stream) {
    const float* x = (const float*)d_in[0];   // [16,128,28,28]
    const float* W = (const float*)d_in[1];   // [128,128,3,3]
    float* out = (float*)d_out;               // [16,128,28,28]
    float* ws  = (float*)d_ws;

    int split = 0;
    if (ws_size >= (size_t)8 * SLAB * sizeof(float))      split = 8;  // 51.4 MB
    else if (ws_size >= (size_t)4 * SLAB * sizeof(float)) split = 4;  // 25.7 MB

    if (split) {
        dim3 grid(NMT, 1, split);             // 196 x split 4-wave blocks
        adder2d_main<<<grid, 256, 0, stream>>>(x, W, ws, (C_ / BC) / split, 0);
        adder2d_combine<<<SLAB / 4 / 256, 256, 0, stream>>>(ws, out, split);
    } else {
        dim3 grid(NMT, 1, 1);                 // fallback: direct, full K
        adder2d_main<<<grid, 256, 0, stream>>>(x, W, out, C_ / BC, 1);
    }
}